// Round 1
// baseline (553.387 us; speedup 1.0000x reference)
//
#include <hip/hip_runtime.h>

#define TT    20000
#define CCH   2500        // TT / 8
#define RROWS 2501
#define NDATA 2000
#define MSZ   262144      // 512*512

typedef unsigned short u16;
typedef unsigned int   u32;
using f32x4 = __attribute__((ext_vector_type(4))) float;
using s16x8 = __attribute__((ext_vector_type(8))) short;

// workspace layout (floats)
static constexpr size_t OFF_HT  = 0;                   // HT = (30A)^T ; reused for M32T
static constexpr size_t OFF_H2T = (size_t)MSZ;         // H^2 T        ; reused for M16T
static constexpr size_t OFF_MP  = 2*(size_t)MSZ;       // M1T..M8T
static constexpr size_t OFF_SQ  = 10*(size_t)MSZ;      // M64T
static constexpr size_t OFF_VEC = 12*(size_t)MSZ;      // v,w1,w2,w3,g,c,u1,u2 (8x512)
static constexpr size_t OFF_FJ  = OFF_VEC + 4096;      // 8 x 40 x 512
static constexpr size_t OFF_AL  = OFF_FJ + 163840;     // 20000 x 5
static constexpr size_t OFF_SA  = OFF_AL + 102400;     // 2501 x 512
static constexpr size_t OFF_SB  = OFF_SA + (size_t)RROWS*512;  // scan ping-pong; reused as Mbf (bf16) after scan4

__device__ __forceinline__ u16 f2bf(float f) {
    u32 u = __float_as_uint(f);
    u += 0x7fff + ((u >> 16) & 1);      // RNE; inputs are finite
    return (u16)(u >> 16);
}

#define MICRO_FMA(a, b) do { \
  acc0.x += (a).x*(b).x; acc0.y += (a).x*(b).y; acc0.z += (a).x*(b).z; acc0.w += (a).x*(b).w; \
  acc1.x += (a).y*(b).x; acc1.y += (a).y*(b).y; acc1.z += (a).y*(b).z; acc1.w += (a).y*(b).w; \
  acc2.x += (a).z*(b).x; acc2.y += (a).z*(b).y; acc2.z += (a).z*(b).z; acc2.w += (a).z*(b).w; \
  acc3.x += (a).w*(b).x; acc3.y += (a).w*(b).y; acc3.z += (a).w*(b).z; acc3.w += (a).w*(b).w; \
} while (0)

#define DECL_GEMM_VARS() \
    int t = threadIdx.x; \
    int tx = t & 15, ty = t >> 4; \
    int ar = t & 63, ak4 = (t >> 6) * 4; \
    int bk = t >> 4, bc4 = (t & 15) * 4; \
    float4 acc0 = {0,0,0,0}, acc1 = {0,0,0,0}, acc2 = {0,0,0,0}, acc3 = {0,0,0,0}; \
    (void)tx; (void)ty; (void)ar; (void)ak4; (void)bk; (void)bc4

// double-buffered 64x64x512 K-loop — for LOW-OCCUPANCY launches (<=2 blocks/CU):
// hides global-load latency that single-buffer exposes every iter (r5/r6 A/B).
#define GEMM_CORE_DB(LOADA, LOADB) \
    { float4 ra = LOADA(0); float4 rbv = LOADB(0); \
    As[0][ak4+0][ar]=ra.x; As[0][ak4+1][ar]=ra.y; As[0][ak4+2][ar]=ra.z; As[0][ak4+3][ar]=ra.w; \
    *(float4*)&Bs[0][bk][bc4] = rbv; \
    for (int kt = 1; kt <= 32; kt++) { \
        __syncthreads(); \
        const int cur = (kt - 1) & 1; \
        if (kt < 32) { ra = LOADA(kt); rbv = LOADB(kt); } \
        _Pragma("unroll") \
        for (int kk = 0; kk < 16; kk++) { \
            float4 a = *(const float4*)&As[cur][kk][ty*4]; \
            float4 b = *(const float4*)&Bs[cur][kk][tx*4]; \
            MICRO_FMA(a, b); \
        } \
        if (kt < 32) { const int nb = kt & 1; \
            As[nb][ak4+0][ar]=ra.x; As[nb][ak4+1][ar]=ra.y; As[nb][ak4+2][ar]=ra.z; As[nb][ak4+3][ar]=ra.w; \
            *(float4*)&Bs[nb][bk][bc4] = rbv; } \
    } }

// Z = A @ B, one 64x64 tile (idx: 8x8)
__device__ __forceinline__ void pow_tile(const float* __restrict__ Ap,
                                         const float* __restrict__ Bp,
                                         float* __restrict__ Zp, int idx) {
    __shared__ float As[2][16][68], Bs[2][16][68];
    DECL_GEMM_VARS();
    int rb = (idx >> 3) * 64, cb = (idx & 7) * 64;
#define LA(kt) (*(const float4*)&Ap[(size_t)(rb+ar)*512 + (kt)*16 + ak4])
#define LB(kt) (*(const float4*)&Bp[(size_t)((kt)*16+bk)*512 + cb + bc4])
    GEMM_CORE_DB(LA, LB)
#undef LA
#undef LB
    size_t zb = (size_t)(rb + ty*4)*512 + cb + tx*4;
    *(float4*)&Zp[zb]        = acc0;
    *(float4*)&Zp[zb + 512]  = acc1;
    *(float4*)&Zp[zb + 1024] = acc2;
    *(float4*)&Zp[zb + 1536] = acc3;
}

// y[rb..rb+128) : y[r] = sum_k MT[k,r] x[k]; optional g-combine
__device__ __forceinline__ void matvecT128(const float* __restrict__ MT,
                                           const float* __restrict__ x,
                                           float* __restrict__ y, int rb,
                                           const float* __restrict__ gc,
                                           const float* __restrict__ gu1,
                                           const float* __restrict__ gu2) {
    __shared__ float xs[512];
    __shared__ float red2[2][128];
    int t = threadIdx.x;
    xs[t] = x[t]; xs[t + 256] = x[t + 256];
    __syncthreads();
    int rl = t & 127, h = t >> 7;
    size_t col = (size_t)rb + rl;
    float acc = 0.f;
    int k0 = h << 8;
    #pragma unroll 4
    for (int k = k0; k < k0 + 256; k++) acc += MT[(size_t)k*512 + col] * xs[k];
    red2[h][rl] = acc;
    __syncthreads();
    if (t < 128) {
        float s = red2[0][t] + red2[1][t];
        int r = rb + t;
        if (gc) y[r] = 30.f * (gc[r] + 0.5f*gu1[r] + (1.f/6.f)*gu2[r] + (1.f/24.f)*s);
        else    y[r] = s;
    }
}

__device__ __forceinline__ float interp1(float tt, const float* __restrict__ xp,
                                         const float* __restrict__ fp) {
    if (tt <= xp[0]) return fp[0];
    if (tt >= xp[NDATA-1]) return fp[NDATA-1];
    int lo = 0, hi = NDATA - 1;
    while (hi - lo > 1) { int mid = (lo + hi) >> 1; if (xp[mid] <= tt) lo = mid; else hi = mid; }
    float x0 = xp[lo], x1 = xp[lo+1];
    return fp[lo] + (fp[lo+1] - fp[lo]) * (tt - x0) / (x1 - x0);
}

// stage 1: HT=(30A)^T (256 blks) + v,c (1) + out0/SA0 (1) + alphas (79)
__global__ __launch_bounds__(256) void k_setup(const float* __restrict__ A,
        const float* __restrict__ B, const float* __restrict__ Q,
        const float* __restrict__ te, const float* __restrict__ Tt,
        const float* __restrict__ Tv, const float* __restrict__ iv,
        float* __restrict__ HT, float* __restrict__ vec, float* __restrict__ AL,
        float* __restrict__ out, float* __restrict__ SA) {
    int bx = blockIdx.x, t = threadIdx.x;
    if (bx < 256) {
        __shared__ float Ts[32][33];
        int tr = bx >> 4, tc = bx & 15;
        int rl = t >> 3, cl4 = (t & 7) * 4;
        float4 a = *(const float4*)&A[(size_t)(tr*32 + rl)*512 + tc*32 + cl4];
        Ts[rl][cl4+0] = 30.f*a.x; Ts[rl][cl4+1] = 30.f*a.y;
        Ts[rl][cl4+2] = 30.f*a.z; Ts[rl][cl4+3] = 30.f*a.w;
        __syncthreads();
        float4 o;
        o.x = Ts[cl4+0][rl]; o.y = Ts[cl4+1][rl]; o.z = Ts[cl4+2][rl]; o.w = Ts[cl4+3][rl];
        *(float4*)&HT[(size_t)(tc*32 + rl)*512 + tr*32 + cl4] = o;
    } else if (bx == 256) {
        for (int i = t; i < 512; i += 256) {
            float v = B[i*9];
            float c = 0.f;
            #pragma unroll
            for (int j = 0; j < 8; j++) c += B[i*9 + 1 + j] * Q[j];
            vec[i] = v;          // v
            vec[2560 + i] = c;   // c
        }
    } else if (bx == 257) {
        for (int i = t; i < 512; i += 256) { out[i] = iv[i]; SA[i] = iv[i]; }
    } else {
        int n = (bx - 258) * 256 + t;
        if (n >= TT) return;
        float* a = AL + (size_t)n * 5;
        if (n == TT - 1) { a[0]=a[1]=a[2]=a[3]=a[4]=0.f; return; }  // padding step
        float tt = te[n];
        float T1 = interp1(tt, Tt, Tv);
        float T2 = interp1(tt + 10.f, Tt, Tv);
        float T3 = interp1(tt + 20.f, Tt, Tv);
        float T4 = interp1(tt + 30.f, Tt, Tv);
        a[0] = 3.75f * (T1 + 3.f*T2 + 3.f*T3 + T4);
        a[1] = 3.75f * (T1 + 2.f*T2 + T3);
        a[2] = 3.75f * (T1*(1.f/3.f) + T2);
        a[3] = 1.25f * T1;
        a[4] = 1.f;
    }
}

// stage 2: H2T = HT@HT  +  kv1 (w1=Hv, u1=Hc)
__global__ __launch_bounds__(256) void k_h2kv(const float* __restrict__ HT,
                                              float* __restrict__ H2T,
                                              float* __restrict__ vec) {
    int bx = blockIdx.x;
    if (bx < 64) { pow_tile(HT, HT, H2T, bx); return; }
    int sub = bx - 64, which = sub >> 2, rb = (sub & 3) * 128;
    if (which == 0) matvecT128(HT, vec,        vec + 512,  rb, 0, 0, 0);   // w1
    else            matvecT128(HT, vec + 2560, vec + 3072, rb, 0, 0, 0);   // u1
}

// stage 3: M1T = I + HT + CT@H2T (CT = I/2 + HT/6 + H2T/24 on the fly) + kv2
__global__ __launch_bounds__(256) void k_m1kv(const float* __restrict__ HT,
                                              const float* __restrict__ H2T,
                                              float* __restrict__ M1T,
                                              float* __restrict__ vec) {
    int bx = blockIdx.x;
    if (bx < 64) {
        __shared__ float As[2][16][68], Bs[2][16][68];
        DECL_GEMM_VARS();
        int rb = (bx >> 3) * 64, cb = (bx & 7) * 64;
#define LA(kt) ({ size_t off = (size_t)(rb+ar)*512 + (kt)*16 + ak4; \
        float4 h  = *(const float4*)&HT[off]; \
        float4 h2 = *(const float4*)&H2T[off]; \
        float4 r_; \
        r_.x = h.x*(1.f/6.f) + h2.x*(1.f/24.f); r_.y = h.y*(1.f/6.f) + h2.y*(1.f/24.f); \
        r_.z = h.z*(1.f/6.f) + h2.z*(1.f/24.f); r_.w = h.w*(1.f/6.f) + h2.w*(1.f/24.f); \
        int dd = (rb+ar) - ((kt)*16 + ak4); \
        if (dd >= 0 && dd < 4) (&r_.x)[dd] += 0.5f; \
        r_; })
#define LB(kt) (*(const float4*)&H2T[(size_t)((kt)*16+bk)*512 + cb + bc4])
        GEMM_CORE_DB(LA, LB)
#undef LA
#undef LB
        int col = cb + tx*4;
        #pragma unroll
        for (int i = 0; i < 4; i++) {
            int r = rb + ty*4 + i;
            float4 h = *(const float4*)&HT[(size_t)r*512 + col];
            float4* ac = (i==0) ? &acc0 : (i==1) ? &acc1 : (i==2) ? &acc2 : &acc3;
            ac->x += h.x + (r == col+0 ? 1.f : 0.f);
            ac->y += h.y + (r == col+1 ? 1.f : 0.f);
            ac->z += h.z + (r == col+2 ? 1.f : 0.f);
            ac->w += h.w + (r == col+3 ? 1.f : 0.f);
            *(float4*)&M1T[(size_t)r*512 + col] = *ac;
        }
        return;
    }
    int sub = bx - 64, which = sub >> 2, rb = (sub & 3) * 128;
    if (which == 0) matvecT128(HT, vec + 512,  vec + 1024, rb, 0, 0, 0);   // w2
    else            matvecT128(HT, vec + 3072, vec + 3584, rb, 0, 0, 0);   // u2
}

// stage 4: M2T = M1T@M1T + kv3 (w3; g via in-flight u3)
__global__ __launch_bounds__(256) void k_m2kv(const float* __restrict__ M1T,
                                              float* __restrict__ M2T,
                                              const float* __restrict__ HT,
                                              float* __restrict__ vec) {
    int bx = blockIdx.x;
    if (bx < 64) { pow_tile(M1T, M1T, M2T, bx); return; }
    int sub = bx - 64, which = sub >> 2, rb = (sub & 3) * 128;
    if (which == 0) matvecT128(HT, vec + 1024, vec + 1536, rb, 0, 0, 0);   // w3
    else matvecT128(HT, vec + 3584, vec + 2048, rb,
                    vec + 2560, vec + 3072, vec + 3584);                   // g
}

// stages 5/6: batched Z_sel = A @ B_sel
__global__ __launch_bounds__(256) void k_pow(const float* __restrict__ A,
                                             const float* __restrict__ B0,
                                             float* __restrict__ Z0) {
    int sel = blockIdx.x >> 6;
    pow_tile(A, B0 + (size_t)sel*MSZ, Z0 + (size_t)sel*MSZ, blockIdx.x & 63);
}

// stage 7: wgen -> FJ (all diagonals)  +  M16 = M8^2
__global__ __launch_bounds__(256) void k_wgen_sq(const float* __restrict__ vec,
                                                 const float* __restrict__ MP,
                                                 float* __restrict__ FJ,
                                                 const float* __restrict__ P,
                                                 float* __restrict__ Pout) {
    int bx = blockIdx.x;
    if (bx >= 64) { pow_tile(P, P, Pout, bx - 64); return; }
    int d = bx >> 3, cb = (bx & 7) * 64;
    int t = threadIdx.x;
    if (d == 0) {
        for (int idx = t; idx < 320; idx += 256) {
            int r = idx >> 6, c = idx & 63;
            float s = vec[(size_t)r*512 + cb + c];
            #pragma unroll
            for (int i = 0; i < 8; i++)
                FJ[((size_t)i*40 + i*5 + r)*512 + cb + c] = s;
        }
        for (int j = 0; j < 7; j++)
            for (int i = j + 1; i < 8; i++)
                for (int idx = t; idx < 320; idx += 256) {
                    int r = idx >> 6, c = idx & 63;
                    FJ[((size_t)j*40 + i*5 + r)*512 + cb + c] = 0.f;
                }
        return;
    }
    __shared__ float Ws[5][512];
    __shared__ float red4[4][5][64];
    const float* Mj = MP + (size_t)(d - 1)*MSZ;
    for (int e = t; e < 2560; e += 256) Ws[e >> 9][e & 511] = vec[e];
    __syncthreads();
    int col = t & 63, kq = t >> 6, k0 = kq * 128;
    float acc[5] = {0.f, 0.f, 0.f, 0.f, 0.f};
    #pragma unroll 4
    for (int k = k0; k < k0 + 128; k++) {
        float m = Mj[(size_t)k*512 + cb + col];
        acc[0] += Ws[0][k]*m; acc[1] += Ws[1][k]*m; acc[2] += Ws[2][k]*m;
        acc[3] += Ws[3][k]*m; acc[4] += Ws[4][k]*m;
    }
    #pragma unroll
    for (int r = 0; r < 5; r++) red4[kq][r][col] = acc[r];
    __syncthreads();
    for (int idx = t; idx < 320; idx += 256) {
        int r = idx >> 6, c = idx & 63;
        float s = red4[0][r][c] + red4[1][r][c] + red4[2][r][c] + red4[3][r][c];
        for (int i = 0; i + d < 8; i++)
            FJ[((size_t)(i + d)*40 + i*5 + r)*512 + cb + c] = s;
    }
}

// stage 8: E = ALhat(2500x40) @ GT(=FJ[7]) -> SA rows 1..2500  +  M32 = M16^2
__global__ __launch_bounds__(256) void k_e40_sq(const float* __restrict__ AL,
                                                const float* __restrict__ FJ,
                                                float* __restrict__ SA1,
                                                const float* __restrict__ P,
                                                float* __restrict__ Pout) {
    int bx = blockIdx.x;
    if (bx >= 320) { pow_tile(P, P, Pout, bx - 320); return; }
    const float* GT = FJ + (size_t)7*40*512;
    int kb = (bx >> 3) * 64, cb = (bx & 7) * 64;
    __shared__ float Ah[64][41], Bsv[40][68];
    int t = threadIdx.x;
    int tx = t & 15, ty = t >> 4;
    #pragma unroll
    for (int m = 0; m < 10; m++) {
        int e = t + 256*m;
        int row = e / 40, q = e - 40*row;
        float v = 0.f;
        if (kb + row < CCH) v = AL[(size_t)(kb + row)*40 + q];
        Ah[row][q] = v;
        int fq = e >> 6, fc = e & 63;
        Bsv[fq][fc] = GT[(size_t)fq*512 + cb + fc];
    }
    __syncthreads();
    float4 acc0 = {0,0,0,0}, acc1 = {0,0,0,0}, acc2 = {0,0,0,0}, acc3 = {0,0,0,0};
    #pragma unroll 8
    for (int q = 0; q < 40; q++) {
        float4 b = *(const float4*)&Bsv[q][tx*4];
        float a0 = Ah[ty*4+0][q], a1 = Ah[ty*4+1][q];
        float a2 = Ah[ty*4+2][q], a3 = Ah[ty*4+3][q];
        acc0.x += a0*b.x; acc0.y += a0*b.y; acc0.z += a0*b.z; acc0.w += a0*b.w;
        acc1.x += a1*b.x; acc1.y += a1*b.y; acc1.z += a1*b.z; acc1.w += a1*b.w;
        acc2.x += a2*b.x; acc2.y += a2*b.y; acc2.z += a2*b.z; acc2.w += a2*b.w;
        acc3.x += a3*b.x; acc3.y += a3*b.y; acc3.z += a3*b.z; acc3.w += a3*b.w;
    }
    int col = cb + tx*4;
    #pragma unroll
    for (int i = 0; i < 4; i++) {
        int k = kb + ty*4 + i;
        if (k < CCH) {
            float4 a = (i==0) ? acc0 : (i==1) ? acc1 : (i==2) ? acc2 : acc3;
            *(float4*)&SA1[(size_t)k*512 + col] = a;
        }
    }
}

// stages 9..12: scan level (Aout[k] = Ain[k] + Ain[k-shift]@QT)  + optional fused pow
__global__ __launch_bounds__(256) void k_scan_sq(const float* __restrict__ Ain,
                                                 float* __restrict__ Aout,
                                                 const float* __restrict__ QT, int shift,
                                                 const float* __restrict__ P,
                                                 float* __restrict__ Pout) {
    int bx = blockIdx.x;
    if (bx >= 320) { pow_tile(P, P, Pout, bx - 320); return; }
    __shared__ float As[2][16][68], Bs[2][16][68];
    DECL_GEMM_VARS();
    int kb = (bx >> 3) * 64, cb = (bx & 7) * 64;
    int xr = kb + ar - shift;
    bool aval = (xr >= 0) && (kb + ar < RROWS);
#define LA(kt) ({ float4 z = {0,0,0,0}; \
        if (aval) z = *(const float4*)&Ain[(size_t)xr*512 + (kt)*16 + ak4]; z; })
#define LB(kt) (*(const float4*)&QT[(size_t)((kt)*16+bk)*512 + cb + bc4])
    GEMM_CORE_DB(LA, LB)
#undef LA
#undef LB
    int col = cb + tx*4;
    #pragma unroll
    for (int i = 0; i < 4; i++) {
        int krow = kb + ty*4 + i;
        if (krow < RROWS) {
            float4 own = *(const float4*)&Ain[(size_t)krow*512 + col];
            float4 a = (i==0) ? acc0 : (i==1) ? acc1 : (i==2) ? acc2 : acc3;
            float4 res = {own.x + a.x, own.y + a.y, own.z + a.z, own.w + a.w};
            *(float4*)&Aout[(size_t)krow*512 + col] = res;
        }
    }
}

// prep for MFMA final: Mbf[j][c][k] = bf16( M^{j+1}[c][k] ) = bf16( MT_j[k][c] )
// (transpose + cast the 8 power matrices into B^T layout, k-contiguous rows).
// one block = one 64x64 tile; grid 8*64.
__global__ __launch_bounds__(256) void k_mprep(const float* __restrict__ MPin,
                                               u16* __restrict__ Mbf) {
    int j = blockIdx.x >> 6, tile = blockIdx.x & 63;
    int kb = (tile >> 3) * 64, cb = (tile & 7) * 64;
    const float* MT = MPin + (size_t)j * MSZ;
    __shared__ float Ts[64][65];
    int t = threadIdx.x;
    int lr = t >> 4, lc = (t & 15) * 4;
    #pragma unroll
    for (int p = 0; p < 4; p++) {
        float4 v = *(const float4*)&MT[(size_t)(kb + p*16 + lr)*512 + cb + lc];
        Ts[p*16+lr][lc+0] = v.x; Ts[p*16+lr][lc+1] = v.y;
        Ts[p*16+lr][lc+2] = v.z; Ts[p*16+lr][lc+3] = v.w;
    }
    __syncthreads();
    int r = t >> 2, c16 = (t & 3) * 16;          // out row = cb+r, k chunk = kb+c16..+15
    u32 pk[8];
    #pragma unroll
    for (int i = 0; i < 8; i++) {
        u32 a = f2bf(Ts[c16 + 2*i][r]);
        u32 b = f2bf(Ts[c16 + 2*i + 1][r]);
        pk[i] = a | (b << 16);
    }
    u16* dst = Mbf + (size_t)j*MSZ + (size_t)(cb + r)*512 + kb + c16;
    *(uint4*)dst       = make_uint4(pk[0], pk[1], pk[2], pk[3]);
    *(uint4*)(dst + 8) = make_uint4(pk[4], pk[5], pk[6], pk[7]);
}

// stage 13: out[8k+j+1] = SS[k] @ M^{j+1}T + ALhat_k @ FJ_j
// bf16 MFMA main loop (16x16x32, fp32 accum): block tile 128(k-rows) x 64(cols),
// 4 waves x (32x64) wave tiles, K=512 in 16 steps of 32.
// A (=SS fp32) is cast to bf16 in the staging path; B comes pre-transposed+cast
// from k_mprep (k-contiguous per lane for both operands).
// LDS rows padded to 40 bf16 (80 B): 2-way bank aliasing only (free).
// Fragment maps (m89/m91-verified): A/B m,n=lane&15, k=(lane>>4)*8+j;
//                                   D  col=lane&15, row=(lane>>4)*4+reg.
// rank-40 forcing epilogue stays exact fp32 (register-hoisted float4 LDS reads).
__global__ __launch_bounds__(256) void k_final(const float* __restrict__ SS,
                                               const u16* __restrict__ Mbf,
                                               const float* __restrict__ AL,
                                               const float* __restrict__ FJ,
                                               float* __restrict__ out) {
    __shared__ float smem[8448];                 // 33792 B (epilogue union is the max)
    u16* Asu = (u16*)smem;                       // [128][40] bf16 = 10240 B
    u16* Bsu = (u16*)(smem + 2560);              // [64][40]  bf16 =  5120 B
    int t = threadIdx.x;
    int lane = t & 63, w = t >> 6;
    int lo16 = lane & 15, hi = lane >> 4;
    int j = blockIdx.x >> 3;
    int cb = (blockIdx.x & 7) * 64;
    int kb = blockIdx.y * 128;
    const u16* Bm = Mbf + (size_t)j * MSZ;

    f32x4 acc[2][4];
    #pragma unroll
    for (int m = 0; m < 2; m++)
        #pragma unroll
        for (int n = 0; n < 4; n++) acc[m][n] = 0.f;

    int s_row = t >> 3;           // A staging: 0..31 rows/pass
    int s_k4  = (t & 7) * 4;      // k offset (float4)
    int b_row = t >> 2;           // B staging: 0..63 rows
    int b_k8  = (t & 3) * 8;      // k offset (8 bf16)

    for (int kt = 0; kt < 16; kt++) {
        __syncthreads();
        // A: SS fp32 -> bf16, 128 rows x 32 k
        #pragma unroll
        for (int p = 0; p < 4; p++) {
            int r = p*32 + s_row;
            float4 v = {0.f, 0.f, 0.f, 0.f};
            if (kb + r < CCH) v = *(const float4*)&SS[(size_t)(kb+r)*512 + kt*32 + s_k4];
            uint2 pk;
            pk.x = (u32)f2bf(v.x) | ((u32)f2bf(v.y) << 16);
            pk.y = (u32)f2bf(v.z) | ((u32)f2bf(v.w) << 16);
            *(uint2*)&Asu[r*40 + s_k4] = pk;
        }
        // B: already bf16, 64 rows x 32 k
        {
            uint4 v = *(const uint4*)&Bm[(size_t)(cb + b_row)*512 + kt*32 + b_k8];
            *(uint4*)&Bsu[b_row*40 + b_k8] = v;
        }
        __syncthreads();
        s16x8 a0 = *(const s16x8*)&Asu[(w*32      + lo16)*40 + hi*8];
        s16x8 a1 = *(const s16x8*)&Asu[(w*32 + 16 + lo16)*40 + hi*8];
        #pragma unroll
        for (int n = 0; n < 4; n++) {
            s16x8 b = *(const s16x8*)&Bsu[(n*16 + lo16)*40 + hi*8];
            acc[0][n] = __builtin_amdgcn_mfma_f32_16x16x32_bf16(a0, b, acc[0][n], 0, 0, 0);
            acc[1][n] = __builtin_amdgcn_mfma_f32_16x16x32_bf16(a1, b, acc[1][n], 0, 0, 0);
        }
    }
    __syncthreads();
    // epilogue staging (smem reused): Ah 128x44 f32, Fs (transposed) 64x44 f32
    float (*Ah)[44] = (float(*)[44])smem;                // 22528 B
    float (*Fs)[44] = (float(*)[44])(smem + 5632);       // 11264 B
    {
        int row = t >> 1, half = t & 1;
        #pragma unroll
        for (int i = 0; i < 5; i++) {
            float4 v = {0.f, 0.f, 0.f, 0.f};
            if (kb + row < CCH) v = *(const float4*)&AL[(size_t)(kb+row)*40 + half*20 + i*4];
            *(float4*)&Ah[row][half*20 + i*4] = v;
        }
        #pragma unroll
        for (int m = 0; m < 10; m++) {
            int e = t + 256*m;                           // 2560 = 40q x 64c
            int q = e >> 6, c = e & 63;
            Fs[c][q] = FJ[(size_t)j*40*512 + (size_t)q*512 + cb + c];
        }
    }
    __syncthreads();
    // rank-40 add: acc[m][n][r] += sum_q Ah[row(m,r)][q] * Fs[col(n)][q]
    #pragma unroll
    for (int cq = 0; cq < 10; cq++) {
        float4 bv[4];
        #pragma unroll
        for (int n = 0; n < 4; n++) bv[n] = *(const float4*)&Fs[n*16 + lo16][cq*4];
        #pragma unroll
        for (int m = 0; m < 2; m++) {
            #pragma unroll
            for (int r = 0; r < 4; r++) {
                float4 av = *(const float4*)&Ah[w*32 + m*16 + hi*4 + r][cq*4];
                #pragma unroll
                for (int n = 0; n < 4; n++) {
                    acc[m][n][r] += av.x*bv[n].x + av.y*bv[n].y + av.z*bv[n].z + av.w*bv[n].w;
                }
            }
        }
    }
    // store: row = kb + w*32 + m*16 + hi*4 + r ; col = cb + n*16 + lo16
    #pragma unroll
    for (int m = 0; m < 2; m++) {
        #pragma unroll
        for (int r = 0; r < 4; r++) {
            int k = kb + w*32 + m*16 + hi*4 + r;
            int n_out = 8*k + j + 1;
            if (k < CCH && n_out < TT) {
                #pragma unroll
                for (int n = 0; n < 4; n++)
                    out[(size_t)n_out*512 + cb + n*16 + lo16] = acc[m][n][r];
            }
        }
    }
}

extern "C" void kernel_launch(void* const* d_in, const int* in_sizes, int n_in,
                              void* d_out, int out_size, void* d_ws, size_t ws_size,
                              hipStream_t stream) {
    const float* A  = (const float*)d_in[0];
    const float* B  = (const float*)d_in[1];
    const float* Q  = (const float*)d_in[2];
    const float* Tt = (const float*)d_in[3];
    const float* Tv = (const float*)d_in[4];
    const float* iv = (const float*)d_in[5];
    const float* te = (const float*)d_in[6];
    float* out = (float*)d_out;
    float* w = (float*)d_ws;

    float* HT  = w + OFF_HT;
    float* H2T = w + OFF_H2T;
    float* MP  = w + OFF_MP;
    float* SQ  = w + OFF_SQ;
    float* vec = w + OFF_VEC;
    float* FJ  = w + OFF_FJ;
    float* AL  = w + OFF_AL;
    float* SA  = w + OFF_SA;
    float* SB  = w + OFF_SB;

    float* M16 = H2T;          // reuse (H2T dead after stage 3)
    float* M32 = HT;           // reuse (HT dead after stage 4)
    float* M64 = SQ;
    float* M8  = MP + 7*(size_t)MSZ;
    u16*   Mbf = (u16*)SB;     // reuse (SB dead after scan4): 8*512*512 bf16 = 4 MB <= 5.1 MB

    // 1. setup: HT, v/c, out row0 + SA row0, alphas
    k_setup<<<337, 256, 0, stream>>>(A, B, Q, te, Tt, Tv, iv, HT, vec, AL, out, SA);
    // 2. H2T + (w1,u1)
    k_h2kv<<<72, 256, 0, stream>>>(HT, H2T, vec);
    // 3. M1T + (w2,u2)
    k_m1kv<<<72, 256, 0, stream>>>(HT, H2T, MP, vec);
    // 4. M2T + (w3, g)
    k_m2kv<<<72, 256, 0, stream>>>(MP, MP + MSZ, HT, vec);
    // 5. [M3T,M4T] = M2T @ [M1T,M2T]
    k_pow<<<128, 256, 0, stream>>>(MP + MSZ, MP, MP + 2*(size_t)MSZ);
    // 6. [M5..M8]T = M4T @ [M1..M4]T
    k_pow<<<256, 256, 0, stream>>>(MP + 3*(size_t)MSZ, MP, MP + 4*(size_t)MSZ);
    // 7. FJ (wgen direct) + M16
    k_wgen_sq<<<128, 256, 0, stream>>>(vec, MP, FJ, M8, M16);
    // 8. E -> SA rows 1.. + M32
    k_e40_sq<<<384, 256, 0, stream>>>(AL, FJ, SA + 512, M16, M32);
    // 9..12. scan levels 1,2,4,8 (+ M64 fused in level 1); window-16 truncation
    //        r6-proven (||M^128|| ~ 1e-3, below bf16 grid step)
    k_scan_sq<<<384, 256, 0, stream>>>(SA, SB, M8,  1, M32, M64);
    k_scan_sq<<<320, 256, 0, stream>>>(SB, SA, M16, 2, nullptr, nullptr);
    k_scan_sq<<<320, 256, 0, stream>>>(SA, SB, M32, 4, nullptr, nullptr);
    k_scan_sq<<<320, 256, 0, stream>>>(SB, SA, M64, 8, nullptr, nullptr);
    // 12.5. transpose+cast M^1..M^8 for the MFMA final (into dead SB region)
    k_mprep<<<512, 256, 0, stream>>>(MP, Mbf);
    // 13. final (reads SA; bf16 MFMA main loop + fp32 rank-40 epilogue)
    k_final<<<dim3(64, 20), 256, 0, stream>>>(SA, Mbf, AL, FJ, out);
}

// Round 2
// 542.154 us; speedup vs baseline: 1.0207x; 1.0207x over previous
//
#include <hip/hip_runtime.h>

#define TT    20000
#define CCH   2500        // TT / 8
#define RROWS 2501
#define NDATA 2000
#define MSZ   262144      // 512*512

typedef unsigned short u16;
typedef unsigned int   u32;
using f32x4 = __attribute__((ext_vector_type(4))) float;
using s16x8 = __attribute__((ext_vector_type(8))) short;

// workspace layout (floats)
static constexpr size_t OFF_HT  = 0;                   // HT = (30A)^T ; reused for M32T
static constexpr size_t OFF_H2T = (size_t)MSZ;         // H^2 T        ; reused for M16T
static constexpr size_t OFF_MP  = 2*(size_t)MSZ;       // M1T..M8T
static constexpr size_t OFF_SQ  = 10*(size_t)MSZ;      // M64T
static constexpr size_t OFF_VEC = 12*(size_t)MSZ;      // v,w1,w2,w3,g,c,u1,u2 (8x512)
static constexpr size_t OFF_FJ  = OFF_VEC + 4096;      // 8 x 40 x 512
static constexpr size_t OFF_AL  = OFF_FJ + 163840;     // 20000 x 5
static constexpr size_t OFF_SA  = OFF_AL + 102400;     // 2501 x 512
static constexpr size_t OFF_SB  = OFF_SA + (size_t)RROWS*512;  // scan ping-pong; reused as Mbf (bf16) after scan4

__device__ __forceinline__ u16 f2bf(float f) {
    u32 u = __float_as_uint(f);
    u += 0x7fff + ((u >> 16) & 1);      // RNE; inputs are finite
    return (u16)(u >> 16);
}

#define MICRO_FMA(a, b) do { \
  acc0.x += (a).x*(b).x; acc0.y += (a).x*(b).y; acc0.z += (a).x*(b).z; acc0.w += (a).x*(b).w; \
  acc1.x += (a).y*(b).x; acc1.y += (a).y*(b).y; acc1.z += (a).y*(b).z; acc1.w += (a).y*(b).w; \
  acc2.x += (a).z*(b).x; acc2.y += (a).z*(b).y; acc2.z += (a).z*(b).z; acc2.w += (a).z*(b).w; \
  acc3.x += (a).w*(b).x; acc3.y += (a).w*(b).y; acc3.z += (a).w*(b).z; acc3.w += (a).w*(b).w; \
} while (0)

#define DECL_GEMM_VARS() \
    int t = threadIdx.x; \
    int tx = t & 15, ty = t >> 4; \
    int ar = t & 63, ak4 = (t >> 6) * 4; \
    int bk = t >> 4, bc4 = (t & 15) * 4; \
    float4 acc0 = {0,0,0,0}, acc1 = {0,0,0,0}, acc2 = {0,0,0,0}, acc3 = {0,0,0,0}; \
    (void)tx; (void)ty; (void)ar; (void)ak4; (void)bk; (void)bc4

// double-buffered 64x64x512 K-loop — for LOW-OCCUPANCY launches (<=2 blocks/CU):
// hides global-load latency that single-buffer exposes every iter (r5/r6 A/B).
#define GEMM_CORE_DB(LOADA, LOADB) \
    { float4 ra = LOADA(0); float4 rbv = LOADB(0); \
    As[0][ak4+0][ar]=ra.x; As[0][ak4+1][ar]=ra.y; As[0][ak4+2][ar]=ra.z; As[0][ak4+3][ar]=ra.w; \
    *(float4*)&Bs[0][bk][bc4] = rbv; \
    for (int kt = 1; kt <= 32; kt++) { \
        __syncthreads(); \
        const int cur = (kt - 1) & 1; \
        if (kt < 32) { ra = LOADA(kt); rbv = LOADB(kt); } \
        _Pragma("unroll") \
        for (int kk = 0; kk < 16; kk++) { \
            float4 a = *(const float4*)&As[cur][kk][ty*4]; \
            float4 b = *(const float4*)&Bs[cur][kk][tx*4]; \
            MICRO_FMA(a, b); \
        } \
        if (kt < 32) { const int nb = kt & 1; \
            As[nb][ak4+0][ar]=ra.x; As[nb][ak4+1][ar]=ra.y; As[nb][ak4+2][ar]=ra.z; As[nb][ak4+3][ar]=ra.w; \
            *(float4*)&Bs[nb][bk][bc4] = rbv; } \
    } }

// Z = A @ B, one 64x64 tile (idx: 8x8)
__device__ __forceinline__ void pow_tile(const float* __restrict__ Ap,
                                         const float* __restrict__ Bp,
                                         float* __restrict__ Zp, int idx) {
    __shared__ float As[2][16][68], Bs[2][16][68];
    DECL_GEMM_VARS();
    int rb = (idx >> 3) * 64, cb = (idx & 7) * 64;
#define LA(kt) (*(const float4*)&Ap[(size_t)(rb+ar)*512 + (kt)*16 + ak4])
#define LB(kt) (*(const float4*)&Bp[(size_t)((kt)*16+bk)*512 + cb + bc4])
    GEMM_CORE_DB(LA, LB)
#undef LA
#undef LB
    size_t zb = (size_t)(rb + ty*4)*512 + cb + tx*4;
    *(float4*)&Zp[zb]        = acc0;
    *(float4*)&Zp[zb + 512]  = acc1;
    *(float4*)&Zp[zb + 1024] = acc2;
    *(float4*)&Zp[zb + 1536] = acc3;
}

// y[rb..rb+128) : y[r] = sum_k MT[k,r] x[k]; optional g-combine
__device__ __forceinline__ void matvecT128(const float* __restrict__ MT,
                                           const float* __restrict__ x,
                                           float* __restrict__ y, int rb,
                                           const float* __restrict__ gc,
                                           const float* __restrict__ gu1,
                                           const float* __restrict__ gu2) {
    __shared__ float xs[512];
    __shared__ float red2[2][128];
    int t = threadIdx.x;
    xs[t] = x[t]; xs[t + 256] = x[t + 256];
    __syncthreads();
    int rl = t & 127, h = t >> 7;
    size_t col = (size_t)rb + rl;
    float acc = 0.f;
    int k0 = h << 8;
    #pragma unroll 4
    for (int k = k0; k < k0 + 256; k++) acc += MT[(size_t)k*512 + col] * xs[k];
    red2[h][rl] = acc;
    __syncthreads();
    if (t < 128) {
        float s = red2[0][t] + red2[1][t];
        int r = rb + t;
        if (gc) y[r] = 30.f * (gc[r] + 0.5f*gu1[r] + (1.f/6.f)*gu2[r] + (1.f/24.f)*s);
        else    y[r] = s;
    }
}

__device__ __forceinline__ float interp1(float tt, const float* __restrict__ xp,
                                         const float* __restrict__ fp) {
    if (tt <= xp[0]) return fp[0];
    if (tt >= xp[NDATA-1]) return fp[NDATA-1];
    int lo = 0, hi = NDATA - 1;
    while (hi - lo > 1) { int mid = (lo + hi) >> 1; if (xp[mid] <= tt) lo = mid; else hi = mid; }
    float x0 = xp[lo], x1 = xp[lo+1];
    return fp[lo] + (fp[lo+1] - fp[lo]) * (tt - x0) / (x1 - x0);
}

// stage 1: HT=(30A)^T (256 blks) + v,c (1) + out0/SA0 (1) + alphas (79)
__global__ __launch_bounds__(256) void k_setup(const float* __restrict__ A,
        const float* __restrict__ B, const float* __restrict__ Q,
        const float* __restrict__ te, const float* __restrict__ Tt,
        const float* __restrict__ Tv, const float* __restrict__ iv,
        float* __restrict__ HT, float* __restrict__ vec, float* __restrict__ AL,
        float* __restrict__ out, float* __restrict__ SA) {
    int bx = blockIdx.x, t = threadIdx.x;
    if (bx < 256) {
        __shared__ float Ts[32][33];
        int tr = bx >> 4, tc = bx & 15;
        int rl = t >> 3, cl4 = (t & 7) * 4;
        float4 a = *(const float4*)&A[(size_t)(tr*32 + rl)*512 + tc*32 + cl4];
        Ts[rl][cl4+0] = 30.f*a.x; Ts[rl][cl4+1] = 30.f*a.y;
        Ts[rl][cl4+2] = 30.f*a.z; Ts[rl][cl4+3] = 30.f*a.w;
        __syncthreads();
        float4 o;
        o.x = Ts[cl4+0][rl]; o.y = Ts[cl4+1][rl]; o.z = Ts[cl4+2][rl]; o.w = Ts[cl4+3][rl];
        *(float4*)&HT[(size_t)(tc*32 + rl)*512 + tr*32 + cl4] = o;
    } else if (bx == 256) {
        for (int i = t; i < 512; i += 256) {
            float v = B[i*9];
            float c = 0.f;
            #pragma unroll
            for (int j = 0; j < 8; j++) c += B[i*9 + 1 + j] * Q[j];
            vec[i] = v;          // v
            vec[2560 + i] = c;   // c
        }
    } else if (bx == 257) {
        for (int i = t; i < 512; i += 256) { out[i] = iv[i]; SA[i] = iv[i]; }
    } else {
        int n = (bx - 258) * 256 + t;
        if (n >= TT) return;
        float* a = AL + (size_t)n * 5;
        if (n == TT - 1) { a[0]=a[1]=a[2]=a[3]=a[4]=0.f; return; }  // padding step
        float tt = te[n];
        float T1 = interp1(tt, Tt, Tv);
        float T2 = interp1(tt + 10.f, Tt, Tv);
        float T3 = interp1(tt + 20.f, Tt, Tv);
        float T4 = interp1(tt + 30.f, Tt, Tv);
        a[0] = 3.75f * (T1 + 3.f*T2 + 3.f*T3 + T4);
        a[1] = 3.75f * (T1 + 2.f*T2 + T3);
        a[2] = 3.75f * (T1*(1.f/3.f) + T2);
        a[3] = 1.25f * T1;
        a[4] = 1.f;
    }
}

// stage 2: H2T = HT@HT  +  kv1 (w1=Hv, u1=Hc)
__global__ __launch_bounds__(256) void k_h2kv(const float* __restrict__ HT,
                                              float* __restrict__ H2T,
                                              float* __restrict__ vec) {
    int bx = blockIdx.x;
    if (bx < 64) { pow_tile(HT, HT, H2T, bx); return; }
    int sub = bx - 64, which = sub >> 2, rb = (sub & 3) * 128;
    if (which == 0) matvecT128(HT, vec,        vec + 512,  rb, 0, 0, 0);   // w1
    else            matvecT128(HT, vec + 2560, vec + 3072, rb, 0, 0, 0);   // u1
}

// stage 3: M1T = I + HT + CT@H2T (CT = I/2 + HT/6 + H2T/24 on the fly) + kv2
__global__ __launch_bounds__(256) void k_m1kv(const float* __restrict__ HT,
                                              const float* __restrict__ H2T,
                                              float* __restrict__ M1T,
                                              float* __restrict__ vec) {
    int bx = blockIdx.x;
    if (bx < 64) {
        __shared__ float As[2][16][68], Bs[2][16][68];
        DECL_GEMM_VARS();
        int rb = (bx >> 3) * 64, cb = (bx & 7) * 64;
#define LA(kt) ({ size_t off = (size_t)(rb+ar)*512 + (kt)*16 + ak4; \
        float4 h  = *(const float4*)&HT[off]; \
        float4 h2 = *(const float4*)&H2T[off]; \
        float4 r_; \
        r_.x = h.x*(1.f/6.f) + h2.x*(1.f/24.f); r_.y = h.y*(1.f/6.f) + h2.y*(1.f/24.f); \
        r_.z = h.z*(1.f/6.f) + h2.z*(1.f/24.f); r_.w = h.w*(1.f/6.f) + h2.w*(1.f/24.f); \
        int dd = (rb+ar) - ((kt)*16 + ak4); \
        if (dd >= 0 && dd < 4) (&r_.x)[dd] += 0.5f; \
        r_; })
#define LB(kt) (*(const float4*)&H2T[(size_t)((kt)*16+bk)*512 + cb + bc4])
        GEMM_CORE_DB(LA, LB)
#undef LA
#undef LB
        int col = cb + tx*4;
        #pragma unroll
        for (int i = 0; i < 4; i++) {
            int r = rb + ty*4 + i;
            float4 h = *(const float4*)&HT[(size_t)r*512 + col];
            float4* ac = (i==0) ? &acc0 : (i==1) ? &acc1 : (i==2) ? &acc2 : &acc3;
            ac->x += h.x + (r == col+0 ? 1.f : 0.f);
            ac->y += h.y + (r == col+1 ? 1.f : 0.f);
            ac->z += h.z + (r == col+2 ? 1.f : 0.f);
            ac->w += h.w + (r == col+3 ? 1.f : 0.f);
            *(float4*)&M1T[(size_t)r*512 + col] = *ac;
        }
        return;
    }
    int sub = bx - 64, which = sub >> 2, rb = (sub & 3) * 128;
    if (which == 0) matvecT128(HT, vec + 512,  vec + 1024, rb, 0, 0, 0);   // w2
    else            matvecT128(HT, vec + 3072, vec + 3584, rb, 0, 0, 0);   // u2
}

// stage 4: M2T = M1T@M1T + kv3 (w3; g via in-flight u3)
__global__ __launch_bounds__(256) void k_m2kv(const float* __restrict__ M1T,
                                              float* __restrict__ M2T,
                                              const float* __restrict__ HT,
                                              float* __restrict__ vec) {
    int bx = blockIdx.x;
    if (bx < 64) { pow_tile(M1T, M1T, M2T, bx); return; }
    int sub = bx - 64, which = sub >> 2, rb = (sub & 3) * 128;
    if (which == 0) matvecT128(HT, vec + 1024, vec + 1536, rb, 0, 0, 0);   // w3
    else matvecT128(HT, vec + 3584, vec + 2048, rb,
                    vec + 2560, vec + 3072, vec + 3584);                   // g
}

// stages 5/6: batched Z_sel = A @ B_sel
__global__ __launch_bounds__(256) void k_pow(const float* __restrict__ A,
                                             const float* __restrict__ B0,
                                             float* __restrict__ Z0) {
    int sel = blockIdx.x >> 6;
    pow_tile(A, B0 + (size_t)sel*MSZ, Z0 + (size_t)sel*MSZ, blockIdx.x & 63);
}

// stage 7: wgen -> FJ (all diagonals)  +  M16 = M8^2
__global__ __launch_bounds__(256) void k_wgen_sq(const float* __restrict__ vec,
                                                 const float* __restrict__ MP,
                                                 float* __restrict__ FJ,
                                                 const float* __restrict__ P,
                                                 float* __restrict__ Pout) {
    int bx = blockIdx.x;
    if (bx >= 64) { pow_tile(P, P, Pout, bx - 64); return; }
    int d = bx >> 3, cb = (bx & 7) * 64;
    int t = threadIdx.x;
    if (d == 0) {
        for (int idx = t; idx < 320; idx += 256) {
            int r = idx >> 6, c = idx & 63;
            float s = vec[(size_t)r*512 + cb + c];
            #pragma unroll
            for (int i = 0; i < 8; i++)
                FJ[((size_t)i*40 + i*5 + r)*512 + cb + c] = s;
        }
        for (int j = 0; j < 7; j++)
            for (int i = j + 1; i < 8; i++)
                for (int idx = t; idx < 320; idx += 256) {
                    int r = idx >> 6, c = idx & 63;
                    FJ[((size_t)j*40 + i*5 + r)*512 + cb + c] = 0.f;
                }
        return;
    }
    __shared__ float Ws[5][512];
    __shared__ float red4[4][5][64];
    const float* Mj = MP + (size_t)(d - 1)*MSZ;
    for (int e = t; e < 2560; e += 256) Ws[e >> 9][e & 511] = vec[e];
    __syncthreads();
    int col = t & 63, kq = t >> 6, k0 = kq * 128;
    float acc[5] = {0.f, 0.f, 0.f, 0.f, 0.f};
    #pragma unroll 4
    for (int k = k0; k < k0 + 128; k++) {
        float m = Mj[(size_t)k*512 + cb + col];
        acc[0] += Ws[0][k]*m; acc[1] += Ws[1][k]*m; acc[2] += Ws[2][k]*m;
        acc[3] += Ws[3][k]*m; acc[4] += Ws[4][k]*m;
    }
    #pragma unroll
    for (int r = 0; r < 5; r++) red4[kq][r][col] = acc[r];
    __syncthreads();
    for (int idx = t; idx < 320; idx += 256) {
        int r = idx >> 6, c = idx & 63;
        float s = red4[0][r][c] + red4[1][r][c] + red4[2][r][c] + red4[3][r][c];
        for (int i = 0; i + d < 8; i++)
            FJ[((size_t)(i + d)*40 + i*5 + r)*512 + cb + c] = s;
    }
}

// stage 8: E = ALhat(2500x40) @ GT(=FJ[7]) -> SA rows 1..2500  +  M32 = M16^2
__global__ __launch_bounds__(256) void k_e40_sq(const float* __restrict__ AL,
                                                const float* __restrict__ FJ,
                                                float* __restrict__ SA1,
                                                const float* __restrict__ P,
                                                float* __restrict__ Pout) {
    int bx = blockIdx.x;
    if (bx >= 320) { pow_tile(P, P, Pout, bx - 320); return; }
    const float* GT = FJ + (size_t)7*40*512;
    int kb = (bx >> 3) * 64, cb = (bx & 7) * 64;
    __shared__ float Ah[64][41], Bsv[40][68];
    int t = threadIdx.x;
    int tx = t & 15, ty = t >> 4;
    #pragma unroll
    for (int m = 0; m < 10; m++) {
        int e = t + 256*m;
        int row = e / 40, q = e - 40*row;
        float v = 0.f;
        if (kb + row < CCH) v = AL[(size_t)(kb + row)*40 + q];
        Ah[row][q] = v;
        int fq = e >> 6, fc = e & 63;
        Bsv[fq][fc] = GT[(size_t)fq*512 + cb + fc];
    }
    __syncthreads();
    float4 acc0 = {0,0,0,0}, acc1 = {0,0,0,0}, acc2 = {0,0,0,0}, acc3 = {0,0,0,0};
    #pragma unroll 8
    for (int q = 0; q < 40; q++) {
        float4 b = *(const float4*)&Bsv[q][tx*4];
        float a0 = Ah[ty*4+0][q], a1 = Ah[ty*4+1][q];
        float a2 = Ah[ty*4+2][q], a3 = Ah[ty*4+3][q];
        acc0.x += a0*b.x; acc0.y += a0*b.y; acc0.z += a0*b.z; acc0.w += a0*b.w;
        acc1.x += a1*b.x; acc1.y += a1*b.y; acc1.z += a1*b.z; acc1.w += a1*b.w;
        acc2.x += a2*b.x; acc2.y += a2*b.y; acc2.z += a2*b.z; acc2.w += a2*b.w;
        acc3.x += a3*b.x; acc3.y += a3*b.y; acc3.z += a3*b.z; acc3.w += a3*b.w;
    }
    int col = cb + tx*4;
    #pragma unroll
    for (int i = 0; i < 4; i++) {
        int k = kb + ty*4 + i;
        if (k < CCH) {
            float4 a = (i==0) ? acc0 : (i==1) ? acc1 : (i==2) ? acc2 : acc3;
            *(float4*)&SA1[(size_t)k*512 + col] = a;
        }
    }
}

// stages 9..12: scan level (Aout[k] = Ain[k] + Ain[k-shift]@QT)  + optional fused pow
__global__ __launch_bounds__(256) void k_scan_sq(const float* __restrict__ Ain,
                                                 float* __restrict__ Aout,
                                                 const float* __restrict__ QT, int shift,
                                                 const float* __restrict__ P,
                                                 float* __restrict__ Pout) {
    int bx = blockIdx.x;
    if (bx >= 320) { pow_tile(P, P, Pout, bx - 320); return; }
    __shared__ float As[2][16][68], Bs[2][16][68];
    DECL_GEMM_VARS();
    int kb = (bx >> 3) * 64, cb = (bx & 7) * 64;
    int xr = kb + ar - shift;
    bool aval = (xr >= 0) && (kb + ar < RROWS);
#define LA(kt) ({ float4 z = {0,0,0,0}; \
        if (aval) z = *(const float4*)&Ain[(size_t)xr*512 + (kt)*16 + ak4]; z; })
#define LB(kt) (*(const float4*)&QT[(size_t)((kt)*16+bk)*512 + cb + bc4])
    GEMM_CORE_DB(LA, LB)
#undef LA
#undef LB
    int col = cb + tx*4;
    #pragma unroll
    for (int i = 0; i < 4; i++) {
        int krow = kb + ty*4 + i;
        if (krow < RROWS) {
            float4 own = *(const float4*)&Ain[(size_t)krow*512 + col];
            float4 a = (i==0) ? acc0 : (i==1) ? acc1 : (i==2) ? acc2 : acc3;
            float4 res = {own.x + a.x, own.y + a.y, own.z + a.z, own.w + a.w};
            *(float4*)&Aout[(size_t)krow*512 + col] = res;
        }
    }
}

// prep for MFMA final: Mbf[j][c][k] = bf16( M^{j+1}[c][k] ) = bf16( MT_j[k][c] )
// (transpose + cast the 8 power matrices into B^T layout, k-contiguous rows).
// one block = one 64x64 tile; grid 8*64.
__global__ __launch_bounds__(256) void k_mprep(const float* __restrict__ MPin,
                                               u16* __restrict__ Mbf) {
    int j = blockIdx.x >> 6, tile = blockIdx.x & 63;
    int kb = (tile >> 3) * 64, cb = (tile & 7) * 64;
    const float* MT = MPin + (size_t)j * MSZ;
    __shared__ float Ts[64][65];
    int t = threadIdx.x;
    int lr = t >> 4, lc = (t & 15) * 4;
    #pragma unroll
    for (int p = 0; p < 4; p++) {
        float4 v = *(const float4*)&MT[(size_t)(kb + p*16 + lr)*512 + cb + lc];
        Ts[p*16+lr][lc+0] = v.x; Ts[p*16+lr][lc+1] = v.y;
        Ts[p*16+lr][lc+2] = v.z; Ts[p*16+lr][lc+3] = v.w;
    }
    __syncthreads();
    int r = t >> 2, c16 = (t & 3) * 16;          // out row = cb+r, k chunk = kb+c16..+15
    u32 pk[8];
    #pragma unroll
    for (int i = 0; i < 8; i++) {
        u32 a = f2bf(Ts[c16 + 2*i][r]);
        u32 b = f2bf(Ts[c16 + 2*i + 1][r]);
        pk[i] = a | (b << 16);
    }
    u16* dst = Mbf + (size_t)j*MSZ + (size_t)(cb + r)*512 + kb + c16;
    *(uint4*)dst       = make_uint4(pk[0], pk[1], pk[2], pk[3]);
    *(uint4*)(dst + 8) = make_uint4(pk[4], pk[5], pk[6], pk[7]);
}

// stage 13: out[8k+j+1] = SS[k] @ M^{j+1}T + ALhat_k @ FJ_j
// bf16 MFMA main loop (16x16x32, fp32 accum), register-prefetch pipeline:
//   load kt+1 into regs right after barrier -> compute kt from LDS -> barrier ->
//   write regs to LDS. Global latency hides under the MFMA+LDS-read phase.
// __launch_bounds__(256,4): cap 128 VGPR -> 4 blocks/CU (the r1 version's 256 VGPR
// collapsed occupancy to 2 blocks/CU and serialized the load latency: 170us).
// All LDS staging is uint4-granular (conflict-free-by-schedule patterns).
// Fragment maps (m89/m91-verified): A/B m,n=lane&15, k=(lane>>4)*8+j;
//                                   D  col=lane&15, row=(lane>>4)*4+reg.
// rank-40 forcing epilogue stays exact fp32; cq-loop unroll capped to contain
// register pressure.
__global__ __launch_bounds__(256, 4) void k_final(const float* __restrict__ SS,
                                               const u16* __restrict__ Mbf,
                                               const float* __restrict__ AL,
                                               const float* __restrict__ FJ,
                                               float* __restrict__ out) {
    __shared__ float smem[8448];                 // 33792 B (epilogue union is the max)
    u16* Asu = (u16*)smem;                       // [128][40] bf16 = 10240 B
    u16* Bsu = (u16*)(smem + 2560);              // [64][40]  bf16 =  5120 B
    int t = threadIdx.x;
    int lane = t & 63, w = t >> 6;
    int lo16 = lane & 15, hi = lane >> 4;
    int j = blockIdx.x >> 3;
    int cb = (blockIdx.x & 7) * 64;
    int kb = blockIdx.y * 128;

    int s_r  = t >> 2;               // 0..63
    int s_k8 = (t & 3) * 8;          // 0,8,16,24

    const float* Ar0 = SS + (size_t)(kb + s_r)*512 + s_k8;
    const float* Ar1 = Ar0 + (size_t)64*512;
    const u16*  Brow = Mbf + (size_t)j*MSZ + (size_t)(cb + s_r)*512 + s_k8;
    const bool av0 = (kb + s_r) < CCH;
    const bool av1 = (kb + 64 + s_r) < CCH;

    f32x4 acc[2][4];
    #pragma unroll
    for (int m = 0; m < 2; m++)
        #pragma unroll
        for (int n = 0; n < 4; n++) acc[m][n] = 0.f;

    float4 a00, a01, a10, a11; uint4 bv;
#define LOADK(kt) do { \
    const float4 z4_ = {0.f,0.f,0.f,0.f}; \
    a00 = av0 ? *(const float4*)&Ar0[(kt)*32]     : z4_; \
    a01 = av0 ? *(const float4*)&Ar0[(kt)*32 + 4] : z4_; \
    a10 = av1 ? *(const float4*)&Ar1[(kt)*32]     : z4_; \
    a11 = av1 ? *(const float4*)&Ar1[(kt)*32 + 4] : z4_; \
    bv  = *(const uint4*)&Brow[(size_t)(kt)*32]; \
} while (0)
#define STORE_LDS() do { \
    uint4 p0_, p1_; \
    p0_.x = (u32)f2bf(a00.x) | ((u32)f2bf(a00.y) << 16); \
    p0_.y = (u32)f2bf(a00.z) | ((u32)f2bf(a00.w) << 16); \
    p0_.z = (u32)f2bf(a01.x) | ((u32)f2bf(a01.y) << 16); \
    p0_.w = (u32)f2bf(a01.z) | ((u32)f2bf(a01.w) << 16); \
    p1_.x = (u32)f2bf(a10.x) | ((u32)f2bf(a10.y) << 16); \
    p1_.y = (u32)f2bf(a10.z) | ((u32)f2bf(a10.w) << 16); \
    p1_.z = (u32)f2bf(a11.x) | ((u32)f2bf(a11.y) << 16); \
    p1_.w = (u32)f2bf(a11.z) | ((u32)f2bf(a11.w) << 16); \
    *(uint4*)&Asu[s_r*40 + s_k8]        = p0_; \
    *(uint4*)&Asu[(64 + s_r)*40 + s_k8] = p1_; \
    *(uint4*)&Bsu[s_r*40 + s_k8]        = bv; \
} while (0)

    LOADK(0);
    STORE_LDS();
    for (int kt = 0; kt < 16; kt++) {
        __syncthreads();
        if (kt < 15) LOADK(kt + 1);
        s16x8 fa0 = *(const s16x8*)&Asu[(w*32      + lo16)*40 + hi*8];
        s16x8 fa1 = *(const s16x8*)&Asu[(w*32 + 16 + lo16)*40 + hi*8];
        #pragma unroll
        for (int n = 0; n < 4; n++) {
            s16x8 fb = *(const s16x8*)&Bsu[(n*16 + lo16)*40 + hi*8];
            acc[0][n] = __builtin_amdgcn_mfma_f32_16x16x32_bf16(fa0, fb, acc[0][n], 0, 0, 0);
            acc[1][n] = __builtin_amdgcn_mfma_f32_16x16x32_bf16(fa1, fb, acc[1][n], 0, 0, 0);
        }
        __syncthreads();
        if (kt < 15) STORE_LDS();
    }
#undef LOADK
#undef STORE_LDS

    // epilogue staging (smem reused; main loop ended with __syncthreads)
    float (*Ah)[44] = (float(*)[44])smem;                // 128 x 44 = 22528 B
    float (*Fs)[44] = (float(*)[44])(smem + 5632);       // 64 x 44  = 11264 B
    {
        int row = t >> 1, half = t & 1;
        #pragma unroll
        for (int i = 0; i < 5; i++) {
            float4 v = {0.f, 0.f, 0.f, 0.f};
            if (kb + row < CCH) v = *(const float4*)&AL[(size_t)(kb+row)*40 + half*20 + i*4];
            *(float4*)&Ah[row][half*20 + i*4] = v;
        }
        const float* FJb = FJ + (size_t)j*40*512 + cb;
        #pragma unroll
        for (int p = 0; p < 3; p++) {
            int e = t + 256*p;
            if (e < 640) {
                int c = e & 63, q4 = e >> 6;
                float4 v;
                v.x = FJb[(size_t)(q4*4+0)*512 + c];
                v.y = FJb[(size_t)(q4*4+1)*512 + c];
                v.z = FJb[(size_t)(q4*4+2)*512 + c];
                v.w = FJb[(size_t)(q4*4+3)*512 + c];
                *(float4*)&Fs[c][q4*4] = v;              // Fs[c][q] = FJ[q][c]
            }
        }
    }
    __syncthreads();
    // rank-40 add: acc[m][n][r] += sum_q Ah[row(m,r)][q] * Fs[col(n)][q]
    #pragma unroll 2
    for (int cq = 0; cq < 10; cq++) {
        float4 bq[4];
        #pragma unroll
        for (int n = 0; n < 4; n++) bq[n] = *(const float4*)&Fs[n*16 + lo16][cq*4];
        #pragma unroll
        for (int m = 0; m < 2; m++) {
            #pragma unroll
            for (int r = 0; r < 4; r++) {
                float4 av = *(const float4*)&Ah[w*32 + m*16 + hi*4 + r][cq*4];
                #pragma unroll
                for (int n = 0; n < 4; n++)
                    acc[m][n][r] += av.x*bq[n].x + av.y*bq[n].y + av.z*bq[n].z + av.w*bq[n].w;
            }
        }
    }
    // store: row = kb + w*32 + m*16 + hi*4 + r ; col = cb + n*16 + lo16
    #pragma unroll
    for (int m = 0; m < 2; m++) {
        #pragma unroll
        for (int r = 0; r < 4; r++) {
            int k = kb + w*32 + m*16 + hi*4 + r;
            int n_out = 8*k + j + 1;
            if (k < CCH && n_out < TT) {
                #pragma unroll
                for (int n = 0; n < 4; n++)
                    out[(size_t)n_out*512 + cb + n*16 + lo16] = acc[m][n][r];
            }
        }
    }
}

extern "C" void kernel_launch(void* const* d_in, const int* in_sizes, int n_in,
                              void* d_out, int out_size, void* d_ws, size_t ws_size,
                              hipStream_t stream) {
    const float* A  = (const float*)d_in[0];
    const float* B  = (const float*)d_in[1];
    const float* Q  = (const float*)d_in[2];
    const float* Tt = (const float*)d_in[3];
    const float* Tv = (const float*)d_in[4];
    const float* iv = (const float*)d_in[5];
    const float* te = (const float*)d_in[6];
    float* out = (float*)d_out;
    float* w = (float*)d_ws;

    float* HT  = w + OFF_HT;
    float* H2T = w + OFF_H2T;
    float* MP  = w + OFF_MP;
    float* SQ  = w + OFF_SQ;
    float* vec = w + OFF_VEC;
    float* FJ  = w + OFF_FJ;
    float* AL  = w + OFF_AL;
    float* SA  = w + OFF_SA;
    float* SB  = w + OFF_SB;

    float* M16 = H2T;          // reuse (H2T dead after stage 3)
    float* M32 = HT;           // reuse (HT dead after stage 4)
    float* M64 = SQ;
    float* M8  = MP + 7*(size_t)MSZ;
    u16*   Mbf = (u16*)SB;     // reuse (SB dead after scan4): 8*512*512 bf16 = 4 MB <= 5.1 MB

    // 1. setup: HT, v/c, out row0 + SA row0, alphas
    k_setup<<<337, 256, 0, stream>>>(A, B, Q, te, Tt, Tv, iv, HT, vec, AL, out, SA);
    // 2. H2T + (w1,u1)
    k_h2kv<<<72, 256, 0, stream>>>(HT, H2T, vec);
    // 3. M1T + (w2,u2)
    k_m1kv<<<72, 256, 0, stream>>>(HT, H2T, MP, vec);
    // 4. M2T + (w3, g)
    k_m2kv<<<72, 256, 0, stream>>>(MP, MP + MSZ, HT, vec);
    // 5. [M3T,M4T] = M2T @ [M1T,M2T]
    k_pow<<<128, 256, 0, stream>>>(MP + MSZ, MP, MP + 2*(size_t)MSZ);
    // 6. [M5..M8]T = M4T @ [M1..M4]T
    k_pow<<<256, 256, 0, stream>>>(MP + 3*(size_t)MSZ, MP, MP + 4*(size_t)MSZ);
    // 7. FJ (wgen direct) + M16
    k_wgen_sq<<<128, 256, 0, stream>>>(vec, MP, FJ, M8, M16);
    // 8. E -> SA rows 1.. + M32
    k_e40_sq<<<384, 256, 0, stream>>>(AL, FJ, SA + 512, M16, M32);
    // 9..12. scan levels 1,2,4,8 (+ M64 fused in level 1); window-16 truncation
    //        r6-proven (||M^128|| ~ 1e-3, below bf16 grid step)
    k_scan_sq<<<384, 256, 0, stream>>>(SA, SB, M8,  1, M32, M64);
    k_scan_sq<<<320, 256, 0, stream>>>(SB, SA, M16, 2, nullptr, nullptr);
    k_scan_sq<<<320, 256, 0, stream>>>(SA, SB, M32, 4, nullptr, nullptr);
    k_scan_sq<<<320, 256, 0, stream>>>(SB, SA, M64, 8, nullptr, nullptr);
    // 12.5. transpose+cast M^1..M^8 for the MFMA final (into dead SB region)
    k_mprep<<<512, 256, 0, stream>>>(MP, Mbf);
    // 13. final (reads SA; bf16 MFMA main loop + fp32 rank-40 epilogue)
    k_final<<<dim3(64, 20), 256, 0, stream>>>(SA, Mbf, AL, FJ, out);
}

// Round 3
// 536.991 us; speedup vs baseline: 1.0305x; 1.0096x over previous
//
#include <hip/hip_runtime.h>

#define TT    20000
#define CCH   2500        // TT / 8
#define RROWS 2501
#define NDATA 2000
#define MSZ   262144      // 512*512

typedef unsigned short u16;
typedef unsigned int   u32;
using f32x4 = __attribute__((ext_vector_type(4))) float;
using s16x8 = __attribute__((ext_vector_type(8))) short;

// workspace layout (floats)
static constexpr size_t OFF_HT  = 0;                   // HT = (30A)^T ; reused for M32T
static constexpr size_t OFF_H2T = (size_t)MSZ;         // H^2 T        ; reused for M16T
static constexpr size_t OFF_MP  = 2*(size_t)MSZ;       // M1T..M8T
static constexpr size_t OFF_SQ  = 10*(size_t)MSZ;      // M64T
static constexpr size_t OFF_VEC = 12*(size_t)MSZ;      // v,w1,w2,w3,g,c,u1,u2 (8x512)
static constexpr size_t OFF_FJ  = OFF_VEC + 4096;      // 8 x 40 x 512
static constexpr size_t OFF_AL  = OFF_FJ + 163840;     // 20000 x 5
static constexpr size_t OFF_SA  = OFF_AL + 102400;     // 2501 x 512
static constexpr size_t OFF_SB  = OFF_SA + (size_t)RROWS*512;  // scan ping-pong; reused as Mbf+FJT after scan4

__device__ __forceinline__ u16 f2bf(float f) {
    u32 u = __float_as_uint(f);
    u += 0x7fff + ((u >> 16) & 1);      // RNE; inputs are finite
    return (u16)(u >> 16);
}

#define MICRO_FMA(a, b) do { \
  acc0.x += (a).x*(b).x; acc0.y += (a).x*(b).y; acc0.z += (a).x*(b).z; acc0.w += (a).x*(b).w; \
  acc1.x += (a).y*(b).x; acc1.y += (a).y*(b).y; acc1.z += (a).y*(b).z; acc1.w += (a).y*(b).w; \
  acc2.x += (a).z*(b).x; acc2.y += (a).z*(b).y; acc2.z += (a).z*(b).z; acc2.w += (a).z*(b).w; \
  acc3.x += (a).w*(b).x; acc3.y += (a).w*(b).y; acc3.z += (a).w*(b).z; acc3.w += (a).w*(b).w; \
} while (0)

#define DECL_GEMM_VARS() \
    int t = threadIdx.x; \
    int tx = t & 15, ty = t >> 4; \
    int ar = t & 63, ak4 = (t >> 6) * 4; \
    int bk = t >> 4, bc4 = (t & 15) * 4; \
    float4 acc0 = {0,0,0,0}, acc1 = {0,0,0,0}, acc2 = {0,0,0,0}, acc3 = {0,0,0,0}; \
    (void)tx; (void)ty; (void)ar; (void)ak4; (void)bk; (void)bc4

// double-buffered 64x64x512 K-loop
#define GEMM_CORE_DB(LOADA, LOADB) \
    { float4 ra = LOADA(0); float4 rbv = LOADB(0); \
    As[0][ak4+0][ar]=ra.x; As[0][ak4+1][ar]=ra.y; As[0][ak4+2][ar]=ra.z; As[0][ak4+3][ar]=ra.w; \
    *(float4*)&Bs[0][bk][bc4] = rbv; \
    for (int kt = 1; kt <= 32; kt++) { \
        __syncthreads(); \
        const int cur = (kt - 1) & 1; \
        if (kt < 32) { ra = LOADA(kt); rbv = LOADB(kt); } \
        _Pragma("unroll") \
        for (int kk = 0; kk < 16; kk++) { \
            float4 a = *(const float4*)&As[cur][kk][ty*4]; \
            float4 b = *(const float4*)&Bs[cur][kk][tx*4]; \
            MICRO_FMA(a, b); \
        } \
        if (kt < 32) { const int nb = kt & 1; \
            As[nb][ak4+0][ar]=ra.x; As[nb][ak4+1][ar]=ra.y; As[nb][ak4+2][ar]=ra.z; As[nb][ak4+3][ar]=ra.w; \
            *(float4*)&Bs[nb][bk][bc4] = rbv; } \
    } }

// Z = A @ B, one 64x64 tile (idx: 8x8)
__device__ __forceinline__ void pow_tile(const float* __restrict__ Ap,
                                         const float* __restrict__ Bp,
                                         float* __restrict__ Zp, int idx) {
    __shared__ float As[2][16][68], Bs[2][16][68];
    DECL_GEMM_VARS();
    int rb = (idx >> 3) * 64, cb = (idx & 7) * 64;
#define LA(kt) (*(const float4*)&Ap[(size_t)(rb+ar)*512 + (kt)*16 + ak4])
#define LB(kt) (*(const float4*)&Bp[(size_t)((kt)*16+bk)*512 + cb + bc4])
    GEMM_CORE_DB(LA, LB)
#undef LA
#undef LB
    size_t zb = (size_t)(rb + ty*4)*512 + cb + tx*4;
    *(float4*)&Zp[zb]        = acc0;
    *(float4*)&Zp[zb + 512]  = acc1;
    *(float4*)&Zp[zb + 1024] = acc2;
    *(float4*)&Zp[zb + 1536] = acc3;
}

// y[rb..rb+128) : y[r] = sum_k MT[k,r] x[k]; optional g-combine
__device__ __forceinline__ void matvecT128(const float* __restrict__ MT,
                                           const float* __restrict__ x,
                                           float* __restrict__ y, int rb,
                                           const float* __restrict__ gc,
                                           const float* __restrict__ gu1,
                                           const float* __restrict__ gu2) {
    __shared__ float xs[512];
    __shared__ float red2[2][128];
    int t = threadIdx.x;
    xs[t] = x[t]; xs[t + 256] = x[t + 256];
    __syncthreads();
    int rl = t & 127, h = t >> 7;
    size_t col = (size_t)rb + rl;
    float acc = 0.f;
    int k0 = h << 8;
    #pragma unroll 4
    for (int k = k0; k < k0 + 256; k++) acc += MT[(size_t)k*512 + col] * xs[k];
    red2[h][rl] = acc;
    __syncthreads();
    if (t < 128) {
        float s = red2[0][t] + red2[1][t];
        int r = rb + t;
        if (gc) y[r] = 30.f * (gc[r] + 0.5f*gu1[r] + (1.f/6.f)*gu2[r] + (1.f/24.f)*s);
        else    y[r] = s;
    }
}

__device__ __forceinline__ float interp1(float tt, const float* __restrict__ xp,
                                         const float* __restrict__ fp) {
    if (tt <= xp[0]) return fp[0];
    if (tt >= xp[NDATA-1]) return fp[NDATA-1];
    int lo = 0, hi = NDATA - 1;
    while (hi - lo > 1) { int mid = (lo + hi) >> 1; if (xp[mid] <= tt) lo = mid; else hi = mid; }
    float x0 = xp[lo], x1 = xp[lo+1];
    return fp[lo] + (fp[lo+1] - fp[lo]) * (tt - x0) / (x1 - x0);
}

// stage 1: HT=(30A)^T (256 blks) + v,c (1) + out0/SA0 (1) + alphas (79)
__global__ __launch_bounds__(256) void k_setup(const float* __restrict__ A,
        const float* __restrict__ B, const float* __restrict__ Q,
        const float* __restrict__ te, const float* __restrict__ Tt,
        const float* __restrict__ Tv, const float* __restrict__ iv,
        float* __restrict__ HT, float* __restrict__ vec, float* __restrict__ AL,
        float* __restrict__ out, float* __restrict__ SA) {
    int bx = blockIdx.x, t = threadIdx.x;
    if (bx < 256) {
        __shared__ float Ts[32][33];
        int tr = bx >> 4, tc = bx & 15;
        int rl = t >> 3, cl4 = (t & 7) * 4;
        float4 a = *(const float4*)&A[(size_t)(tr*32 + rl)*512 + tc*32 + cl4];
        Ts[rl][cl4+0] = 30.f*a.x; Ts[rl][cl4+1] = 30.f*a.y;
        Ts[rl][cl4+2] = 30.f*a.z; Ts[rl][cl4+3] = 30.f*a.w;
        __syncthreads();
        float4 o;
        o.x = Ts[cl4+0][rl]; o.y = Ts[cl4+1][rl]; o.z = Ts[cl4+2][rl]; o.w = Ts[cl4+3][rl];
        *(float4*)&HT[(size_t)(tc*32 + rl)*512 + tr*32 + cl4] = o;
    } else if (bx == 256) {
        for (int i = t; i < 512; i += 256) {
            float v = B[i*9];
            float c = 0.f;
            #pragma unroll
            for (int j = 0; j < 8; j++) c += B[i*9 + 1 + j] * Q[j];
            vec[i] = v;          // v
            vec[2560 + i] = c;   // c
        }
    } else if (bx == 257) {
        for (int i = t; i < 512; i += 256) { out[i] = iv[i]; SA[i] = iv[i]; }
    } else {
        int n = (bx - 258) * 256 + t;
        if (n >= TT) return;
        float* a = AL + (size_t)n * 5;
        if (n == TT - 1) { a[0]=a[1]=a[2]=a[3]=a[4]=0.f; return; }  // padding step
        float tt = te[n];
        float T1 = interp1(tt, Tt, Tv);
        float T2 = interp1(tt + 10.f, Tt, Tv);
        float T3 = interp1(tt + 20.f, Tt, Tv);
        float T4 = interp1(tt + 30.f, Tt, Tv);
        a[0] = 3.75f * (T1 + 3.f*T2 + 3.f*T3 + T4);
        a[1] = 3.75f * (T1 + 2.f*T2 + T3);
        a[2] = 3.75f * (T1*(1.f/3.f) + T2);
        a[3] = 1.25f * T1;
        a[4] = 1.f;
    }
}

// stage 2: H2T = HT@HT  +  kv1 (w1=Hv, u1=Hc)
__global__ __launch_bounds__(256) void k_h2kv(const float* __restrict__ HT,
                                              float* __restrict__ H2T,
                                              float* __restrict__ vec) {
    int bx = blockIdx.x;
    if (bx < 64) { pow_tile(HT, HT, H2T, bx); return; }
    int sub = bx - 64, which = sub >> 2, rb = (sub & 3) * 128;
    if (which == 0) matvecT128(HT, vec,        vec + 512,  rb, 0, 0, 0);   // w1
    else            matvecT128(HT, vec + 2560, vec + 3072, rb, 0, 0, 0);   // u1
}

// stage 3: M1T = I + HT + CT@H2T (CT = I/2 + HT/6 + H2T/24 on the fly) + kv2
__global__ __launch_bounds__(256) void k_m1kv(const float* __restrict__ HT,
                                              const float* __restrict__ H2T,
                                              float* __restrict__ M1T,
                                              float* __restrict__ vec) {
    int bx = blockIdx.x;
    if (bx < 64) {
        __shared__ float As[2][16][68], Bs[2][16][68];
        DECL_GEMM_VARS();
        int rb = (bx >> 3) * 64, cb = (bx & 7) * 64;
#define LA(kt) ({ size_t off = (size_t)(rb+ar)*512 + (kt)*16 + ak4; \
        float4 h  = *(const float4*)&HT[off]; \
        float4 h2 = *(const float4*)&H2T[off]; \
        float4 r_; \
        r_.x = h.x*(1.f/6.f) + h2.x*(1.f/24.f); r_.y = h.y*(1.f/6.f) + h2.y*(1.f/24.f); \
        r_.z = h.z*(1.f/6.f) + h2.z*(1.f/24.f); r_.w = h.w*(1.f/6.f) + h2.w*(1.f/24.f); \
        int dd = (rb+ar) - ((kt)*16 + ak4); \
        if (dd >= 0 && dd < 4) (&r_.x)[dd] += 0.5f; \
        r_; })
#define LB(kt) (*(const float4*)&H2T[(size_t)((kt)*16+bk)*512 + cb + bc4])
        GEMM_CORE_DB(LA, LB)
#undef LA
#undef LB
        int col = cb + tx*4;
        #pragma unroll
        for (int i = 0; i < 4; i++) {
            int r = rb + ty*4 + i;
            float4 h = *(const float4*)&HT[(size_t)r*512 + col];
            float4* ac = (i==0) ? &acc0 : (i==1) ? &acc1 : (i==2) ? &acc2 : &acc3;
            ac->x += h.x + (r == col+0 ? 1.f : 0.f);
            ac->y += h.y + (r == col+1 ? 1.f : 0.f);
            ac->z += h.z + (r == col+2 ? 1.f : 0.f);
            ac->w += h.w + (r == col+3 ? 1.f : 0.f);
            *(float4*)&M1T[(size_t)r*512 + col] = *ac;
        }
        return;
    }
    int sub = bx - 64, which = sub >> 2, rb = (sub & 3) * 128;
    if (which == 0) matvecT128(HT, vec + 512,  vec + 1024, rb, 0, 0, 0);   // w2
    else            matvecT128(HT, vec + 3072, vec + 3584, rb, 0, 0, 0);   // u2
}

// stage 4: M2T = M1T@M1T + kv3 (w3; g via in-flight u3)
__global__ __launch_bounds__(256) void k_m2kv(const float* __restrict__ M1T,
                                              float* __restrict__ M2T,
                                              const float* __restrict__ HT,
                                              float* __restrict__ vec) {
    int bx = blockIdx.x;
    if (bx < 64) { pow_tile(M1T, M1T, M2T, bx); return; }
    int sub = bx - 64, which = sub >> 2, rb = (sub & 3) * 128;
    if (which == 0) matvecT128(HT, vec + 1024, vec + 1536, rb, 0, 0, 0);   // w3
    else matvecT128(HT, vec + 3584, vec + 2048, rb,
                    vec + 2560, vec + 3072, vec + 3584);                   // g
}

// stages 5/6: batched Z_sel = A @ B_sel
__global__ __launch_bounds__(256) void k_pow(const float* __restrict__ A,
                                             const float* __restrict__ B0,
                                             float* __restrict__ Z0) {
    int sel = blockIdx.x >> 6;
    pow_tile(A, B0 + (size_t)sel*MSZ, Z0 + (size_t)sel*MSZ, blockIdx.x & 63);
}

// stage 7: wgen -> FJ (all diagonals)  +  M16 = M8^2
__global__ __launch_bounds__(256) void k_wgen_sq(const float* __restrict__ vec,
                                                 const float* __restrict__ MP,
                                                 float* __restrict__ FJ,
                                                 const float* __restrict__ P,
                                                 float* __restrict__ Pout) {
    int bx = blockIdx.x;
    if (bx >= 64) { pow_tile(P, P, Pout, bx - 64); return; }
    int d = bx >> 3, cb = (bx & 7) * 64;
    int t = threadIdx.x;
    if (d == 0) {
        for (int idx = t; idx < 320; idx += 256) {
            int r = idx >> 6, c = idx & 63;
            float s = vec[(size_t)r*512 + cb + c];
            #pragma unroll
            for (int i = 0; i < 8; i++)
                FJ[((size_t)i*40 + i*5 + r)*512 + cb + c] = s;
        }
        for (int j = 0; j < 7; j++)
            for (int i = j + 1; i < 8; i++)
                for (int idx = t; idx < 320; idx += 256) {
                    int r = idx >> 6, c = idx & 63;
                    FJ[((size_t)j*40 + i*5 + r)*512 + cb + c] = 0.f;
                }
        return;
    }
    __shared__ float Ws[5][512];
    __shared__ float red4[4][5][64];
    const float* Mj = MP + (size_t)(d - 1)*MSZ;
    for (int e = t; e < 2560; e += 256) Ws[e >> 9][e & 511] = vec[e];
    __syncthreads();
    int col = t & 63, kq = t >> 6, k0 = kq * 128;
    float acc[5] = {0.f, 0.f, 0.f, 0.f, 0.f};
    #pragma unroll 4
    for (int k = k0; k < k0 + 128; k++) {
        float m = Mj[(size_t)k*512 + cb + col];
        acc[0] += Ws[0][k]*m; acc[1] += Ws[1][k]*m; acc[2] += Ws[2][k]*m;
        acc[3] += Ws[3][k]*m; acc[4] += Ws[4][k]*m;
    }
    #pragma unroll
    for (int r = 0; r < 5; r++) red4[kq][r][col] = acc[r];
    __syncthreads();
    for (int idx = t; idx < 320; idx += 256) {
        int r = idx >> 6, c = idx & 63;
        float s = red4[0][r][c] + red4[1][r][c] + red4[2][r][c] + red4[3][r][c];
        for (int i = 0; i + d < 8; i++)
            FJ[((size_t)(i + d)*40 + i*5 + r)*512 + cb + c] = s;
    }
}

// stage 8: E = ALhat(2500x40) @ GT(=FJ[7]) -> SA rows 1..2500  +  M32 = M16^2
__global__ __launch_bounds__(256) void k_e40_sq(const float* __restrict__ AL,
                                                const float* __restrict__ FJ,
                                                float* __restrict__ SA1,
                                                const float* __restrict__ P,
                                                float* __restrict__ Pout) {
    int bx = blockIdx.x;
    if (bx >= 320) { pow_tile(P, P, Pout, bx - 320); return; }
    const float* GT = FJ + (size_t)7*40*512;
    int kb = (bx >> 3) * 64, cb = (bx & 7) * 64;
    __shared__ float Ah[64][41], Bsv[40][68];
    int t = threadIdx.x;
    int tx = t & 15, ty = t >> 4;
    #pragma unroll
    for (int m = 0; m < 10; m++) {
        int e = t + 256*m;
        int row = e / 40, q = e - 40*row;
        float v = 0.f;
        if (kb + row < CCH) v = AL[(size_t)(kb + row)*40 + q];
        Ah[row][q] = v;
        int fq = e >> 6, fc = e & 63;
        Bsv[fq][fc] = GT[(size_t)fq*512 + cb + fc];
    }
    __syncthreads();
    float4 acc0 = {0,0,0,0}, acc1 = {0,0,0,0}, acc2 = {0,0,0,0}, acc3 = {0,0,0,0};
    #pragma unroll 8
    for (int q = 0; q < 40; q++) {
        float4 b = *(const float4*)&Bsv[q][tx*4];
        float a0 = Ah[ty*4+0][q], a1 = Ah[ty*4+1][q];
        float a2 = Ah[ty*4+2][q], a3 = Ah[ty*4+3][q];
        acc0.x += a0*b.x; acc0.y += a0*b.y; acc0.z += a0*b.z; acc0.w += a0*b.w;
        acc1.x += a1*b.x; acc1.y += a1*b.y; acc1.z += a1*b.z; acc1.w += a1*b.w;
        acc2.x += a2*b.x; acc2.y += a2*b.y; acc2.z += a2*b.z; acc2.w += a2*b.w;
        acc3.x += a3*b.x; acc3.y += a3*b.y; acc3.z += a3*b.z; acc3.w += a3*b.w;
    }
    int col = cb + tx*4;
    #pragma unroll
    for (int i = 0; i < 4; i++) {
        int k = kb + ty*4 + i;
        if (k < CCH) {
            float4 a = (i==0) ? acc0 : (i==1) ? acc1 : (i==2) ? acc2 : acc3;
            *(float4*)&SA1[(size_t)k*512 + col] = a;
        }
    }
}

// stages 9..12: scan level (Aout[k] = Ain[k] + Ain[k-shift]@QT)  + optional fused pow
__global__ __launch_bounds__(256) void k_scan_sq(const float* __restrict__ Ain,
                                                 float* __restrict__ Aout,
                                                 const float* __restrict__ QT, int shift,
                                                 const float* __restrict__ P,
                                                 float* __restrict__ Pout) {
    int bx = blockIdx.x;
    if (bx >= 320) { pow_tile(P, P, Pout, bx - 320); return; }
    __shared__ float As[2][16][68], Bs[2][16][68];
    DECL_GEMM_VARS();
    int kb = (bx >> 3) * 64, cb = (bx & 7) * 64;
    int xr = kb + ar - shift;
    bool aval = (xr >= 0) && (kb + ar < RROWS);
#define LA(kt) ({ float4 z = {0,0,0,0}; \
        if (aval) z = *(const float4*)&Ain[(size_t)xr*512 + (kt)*16 + ak4]; z; })
#define LB(kt) (*(const float4*)&QT[(size_t)((kt)*16+bk)*512 + cb + bc4])
    GEMM_CORE_DB(LA, LB)
#undef LA
#undef LB
    int col = cb + tx*4;
    #pragma unroll
    for (int i = 0; i < 4; i++) {
        int krow = kb + ty*4 + i;
        if (krow < RROWS) {
            float4 own = *(const float4*)&Ain[(size_t)krow*512 + col];
            float4 a = (i==0) ? acc0 : (i==1) ? acc1 : (i==2) ? acc2 : acc3;
            float4 res = {own.x + a.x, own.y + a.y, own.z + a.z, own.w + a.w};
            *(float4*)&Aout[(size_t)krow*512 + col] = res;
        }
    }
}

// prep for MFMA final:
//  blocks 0..511 : Mbf[j][c][k] = bf16( MT_j[k][c] )  (B^T layout, k-contiguous)
//  blocks 512..527: FJT[j][c][q] = FJ[j][q][c]         (f32 transpose for epilogue)
__global__ __launch_bounds__(256) void k_mprep(const float* __restrict__ MPin,
                                               u16* __restrict__ Mbf,
                                               const float* __restrict__ FJ,
                                               float* __restrict__ FJT) {
    int bx = blockIdx.x;
    int t = threadIdx.x;
    if (bx >= 512) {
        int bx2 = bx - 512;
        int j = bx2 >> 1, half = bx2 & 1;
        int col = half*256 + t;
        const float* Fb = FJ + (size_t)j*40*512 + col;
        float* Ft = FJT + (size_t)j*512*40 + (size_t)col*40;
        #pragma unroll 8
        for (int q = 0; q < 40; q++) Ft[q] = Fb[(size_t)q*512];
        return;
    }
    int j = bx >> 6, tile = bx & 63;
    int kb = (tile >> 3) * 64, cb = (tile & 7) * 64;
    const float* MT = MPin + (size_t)j * MSZ;
    __shared__ float Ts[64][65];
    int lr = t >> 4, lc = (t & 15) * 4;
    #pragma unroll
    for (int p = 0; p < 4; p++) {
        float4 v = *(const float4*)&MT[(size_t)(kb + p*16 + lr)*512 + cb + lc];
        Ts[p*16+lr][lc+0] = v.x; Ts[p*16+lr][lc+1] = v.y;
        Ts[p*16+lr][lc+2] = v.z; Ts[p*16+lr][lc+3] = v.w;
    }
    __syncthreads();
    int r = t >> 2, c16 = (t & 3) * 16;          // out row = cb+r, k chunk = kb+c16..+15
    u32 pk[8];
    #pragma unroll
    for (int i = 0; i < 8; i++) {
        u32 a = f2bf(Ts[c16 + 2*i][r]);
        u32 b = f2bf(Ts[c16 + 2*i + 1][r]);
        pk[i] = a | (b << 16);
    }
    u16* dst = Mbf + (size_t)j*MSZ + (size_t)(cb + r)*512 + kb + c16;
    *(uint4*)dst       = make_uint4(pk[0], pk[1], pk[2], pk[3]);
    *(uint4*)(dst + 8) = make_uint4(pk[4], pk[5], pk[6], pk[7]);
}

// stage 13: out[8k+j+1] = SS[k] @ M^{j+1}T + ALhat_k @ FJ_j
// v3 tiling, chosen for the MEMORY PATTERN (r2 evidence: all pipes idle at 163us;
// the invariant across 3 implementations was the scattered 256B-row writes and the
// 400MB cross-XCD cache read amplification):
//  - block = 32 k-rows x ALL 512 cols x ONE j  -> writes 32 complete contiguous
//    2KB output rows (no scatter).
//  - grid (8, 79), j = blockIdx.x -> same-j blocks share an XCD (round-robin),
//    so Mbf_j (512KB) + FJT_j (80KB) stay L2-resident; SS amp drops 64x -> 8x.
//  - acc 2x8 frags = 64 VGPR; register prefetch + sched_barrier(0) so the
//    compiler can't sink the loads (r2's VGPR=56 betrayed exactly that).
__global__ __launch_bounds__(256, 2) void k_final(const float* __restrict__ SS,
                                               const u16* __restrict__ Mbf,
                                               const float* __restrict__ AL,
                                               const float* __restrict__ FJT,
                                               float* __restrict__ out) {
    __shared__ u16 Bsu[512*36];                  // [col][32k +4pad] bf16, 36864 B
    __shared__ u16 Asu[32*36];                   // [row][32k +4pad] bf16,  2304 B
    __shared__ float Ah[32][40];                 // ALhat rows, 5120 B
    int t = threadIdx.x;
    int lane = t & 63, w = t >> 6;
    int lo16 = lane & 15, hi = lane >> 4;
    int j = blockIdx.x;
    int kb = blockIdx.y * 32;

    // staging assignments
    int b_r  = t >> 2;               // 0..63 (x8 passes -> 512 B-rows)
    int b_k8 = (t & 3) * 8;          // u16 k-offset
    int a_r  = t >> 3;               // 0..31 A-rows
    int a_c4 = (t & 7) * 4;          // float k-offset
    const u16* Bb = Mbf + (size_t)j*MSZ;
    const float* Ab = SS + (size_t)(kb + a_r)*512 + a_c4;
    const bool aval = (kb + a_r) < CCH;

    f32x4 acc[2][8];
    #pragma unroll
    for (int m = 0; m < 2; m++)
        #pragma unroll
        for (int n = 0; n < 8; n++) acc[m][n] = 0.f;

    uint4 pb[8]; float4 pa;
#define PREFETCH(kt) do { \
    _Pragma("unroll") \
    for (int p = 0; p < 8; p++) \
        pb[p] = *(const uint4*)&Bb[(size_t)(p*64 + b_r)*512 + (kt)*32 + b_k8]; \
    const float4 z4_ = {0.f,0.f,0.f,0.f}; \
    pa = aval ? *(const float4*)&Ab[(kt)*32] : z4_; \
} while (0)
#define STORE_LDS() do { \
    _Pragma("unroll") \
    for (int p = 0; p < 8; p++) \
        *(uint4*)&Bsu[(p*64 + b_r)*36 + b_k8] = pb[p]; \
    uint2 pk_; \
    pk_.x = (u32)f2bf(pa.x) | ((u32)f2bf(pa.y) << 16); \
    pk_.y = (u32)f2bf(pa.z) | ((u32)f2bf(pa.w) << 16); \
    *(uint2*)&Asu[a_r*36 + a_c4] = pk_; \
} while (0)

    PREFETCH(0);
    for (int kt = 0; kt < 16; kt++) {
        __syncthreads();                 // previous compute done reading LDS
        STORE_LDS();
        __syncthreads();
        if (kt < 15) PREFETCH(kt + 1);   // loads in flight across the compute
        __builtin_amdgcn_sched_barrier(0);
        s16x8 fa0 = *(const s16x8*)&Asu[(lo16)*36 + hi*8];
        s16x8 fa1 = *(const s16x8*)&Asu[(16 + lo16)*36 + hi*8];
        #pragma unroll
        for (int n = 0; n < 8; n++) {
            s16x8 fb = *(const s16x8*)&Bsu[((size_t)(w*128 + n*16 + lo16))*36 + hi*8];
            acc[0][n] = __builtin_amdgcn_mfma_f32_16x16x32_bf16(fa0, fb, acc[0][n], 0, 0, 0);
            acc[1][n] = __builtin_amdgcn_mfma_f32_16x16x32_bf16(fa1, fb, acc[1][n], 0, 0, 0);
        }
    }
#undef PREFETCH
#undef STORE_LDS

    // ---- rank-40 forcing epilogue (exact fp32) ----
    __syncthreads();
    for (int i = t; i < 1280; i += 256) {
        int row = i / 40, q = i - row*40;
        float v = 0.f;
        if (kb + row < CCH) v = AL[(size_t)(kb + row)*40 + q];
        (&Ah[0][0])[i] = v;
    }
    __syncthreads();
    const float* Ft = FJT + (size_t)j*512*40;
    int colb = w*128 + lo16;
    #pragma unroll 2
    for (int q4 = 0; q4 < 10; q4++) {
        float4 fv[8];
        #pragma unroll
        for (int n = 0; n < 8; n++)
            fv[n] = *(const float4*)&Ft[(size_t)(colb + n*16)*40 + q4*4];
        #pragma unroll
        for (int m = 0; m < 2; m++) {
            #pragma unroll
            for (int r = 0; r < 4; r++) {
                float4 av = *(const float4*)&Ah[m*16 + hi*4 + r][q4*4];
                #pragma unroll
                for (int n = 0; n < 8; n++)
                    acc[m][n][r] += av.x*fv[n].x + av.y*fv[n].y + av.z*fv[n].z + av.w*fv[n].w;
            }
        }
    }
    // store: 32 full contiguous 2KB rows; row = 8*(kb+m*16+hi*4+r)+j+1
    #pragma unroll
    for (int m = 0; m < 2; m++) {
        #pragma unroll
        for (int r = 0; r < 4; r++) {
            int k = kb + m*16 + hi*4 + r;
            int n_out = 8*k + j + 1;
            if (k < CCH && n_out < TT) {
                size_t ro = (size_t)n_out*512 + w*128 + lo16;
                #pragma unroll
                for (int n = 0; n < 8; n++)
                    out[ro + n*16] = acc[m][n][r];
            }
        }
    }
}

extern "C" void kernel_launch(void* const* d_in, const int* in_sizes, int n_in,
                              void* d_out, int out_size, void* d_ws, size_t ws_size,
                              hipStream_t stream) {
    const float* A  = (const float*)d_in[0];
    const float* B  = (const float*)d_in[1];
    const float* Q  = (const float*)d_in[2];
    const float* Tt = (const float*)d_in[3];
    const float* Tv = (const float*)d_in[4];
    const float* iv = (const float*)d_in[5];
    const float* te = (const float*)d_in[6];
    float* out = (float*)d_out;
    float* w = (float*)d_ws;

    float* HT  = w + OFF_HT;
    float* H2T = w + OFF_H2T;
    float* MP  = w + OFF_MP;
    float* SQ  = w + OFF_SQ;
    float* vec = w + OFF_VEC;
    float* FJ  = w + OFF_FJ;
    float* AL  = w + OFF_AL;
    float* SA  = w + OFF_SA;
    float* SB  = w + OFF_SB;

    float* M16 = H2T;          // reuse (H2T dead after stage 3)
    float* M32 = HT;           // reuse (HT dead after stage 4)
    float* M64 = SQ;
    float* M8  = MP + 7*(size_t)MSZ;
    u16*   Mbf = (u16*)SB;                    // SB dead after scan4: 4 MB bf16
    float* FJT = SB + 4*(size_t)MSZ;          // + 8x512x40 f32 = 640 KB (SB is 4.88 MB)

    // 1. setup: HT, v/c, out row0 + SA row0, alphas
    k_setup<<<337, 256, 0, stream>>>(A, B, Q, te, Tt, Tv, iv, HT, vec, AL, out, SA);
    // 2. H2T + (w1,u1)
    k_h2kv<<<72, 256, 0, stream>>>(HT, H2T, vec);
    // 3. M1T + (w2,u2)
    k_m1kv<<<72, 256, 0, stream>>>(HT, H2T, MP, vec);
    // 4. M2T + (w3, g)
    k_m2kv<<<72, 256, 0, stream>>>(MP, MP + MSZ, HT, vec);
    // 5. [M3T,M4T] = M2T @ [M1T,M2T]
    k_pow<<<128, 256, 0, stream>>>(MP + MSZ, MP, MP + 2*(size_t)MSZ);
    // 6. [M5..M8]T = M4T @ [M1..M4]T
    k_pow<<<256, 256, 0, stream>>>(MP + 3*(size_t)MSZ, MP, MP + 4*(size_t)MSZ);
    // 7. FJ (wgen direct) + M16
    k_wgen_sq<<<128, 256, 0, stream>>>(vec, MP, FJ, M8, M16);
    // 8. E -> SA rows 1.. + M32
    k_e40_sq<<<384, 256, 0, stream>>>(AL, FJ, SA + 512, M16, M32);
    // 9..12. scan levels 1,2,4,8 (+ M64 fused in level 1); window-16 truncation
    k_scan_sq<<<384, 256, 0, stream>>>(SA, SB, M8,  1, M32, M64);
    k_scan_sq<<<320, 256, 0, stream>>>(SB, SA, M16, 2, nullptr, nullptr);
    k_scan_sq<<<320, 256, 0, stream>>>(SA, SB, M32, 4, nullptr, nullptr);
    k_scan_sq<<<320, 256, 0, stream>>>(SB, SA, M64, 8, nullptr, nullptr);
    // 12.5. transpose+cast M^1..M^8 (bf16 B^T) + FJT (f32) into dead SB region
    k_mprep<<<528, 256, 0, stream>>>(MP, Mbf, FJ, FJT);
    // 13. final (reads SA; bf16 MFMA, j-per-XCD, full-row contiguous writes)
    k_final<<<dim3(8, 79), 256, 0, stream>>>(SA, Mbf, AL, FJT, out);
}